// Round 1
// baseline (313.932 us; speedup 1.0000x reference)
//
#include <hip/hip_runtime.h>
#include <hip/hip_bf16.h>

// Problem constants (from setup_inputs): N=12288, E=393216, D=256, K=16
#define D 256
#define KCL 16
#define EPS 1e-15f

// ---------------- zero counts + diag ----------------
__global__ void zero_k(int* __restrict__ counts, float* __restrict__ diag, int N) {
    int i = blockIdx.x * 256 + threadIdx.x;
    if (i < N) counts[i] = 0;
    if (i < KCL) diag[i] = 0.f;
}

// ---------------- degree histogram ----------------
__global__ void hist_k(const int* __restrict__ dst, int* __restrict__ counts, int E) {
    int e = blockIdx.x * 256 + threadIdx.x;
    if (e < E) atomicAdd(&counts[dst[e]], 1);
}

// ---------------- exclusive scan (single block, 1024 threads) ----------------
__global__ __launch_bounds__(1024) void scan_k(const int* __restrict__ counts,
                                               int* __restrict__ offs,
                                               int* __restrict__ cursor, int N) {
    __shared__ int part[1024];
    int t = threadIdx.x;
    const int CH = (N + 1023) >> 10;   // elems per thread (12 for N=12288)
    int local[16];
    int sum = 0;
    for (int i = 0; i < CH; ++i) {
        int idx = t * CH + i;
        int c = (idx < N) ? counts[idx] : 0;
        local[i] = c; sum += c;
    }
    part[t] = sum;
    __syncthreads();
    for (int off = 1; off < 1024; off <<= 1) {
        int v = (t >= off) ? part[t - off] : 0;
        __syncthreads();
        part[t] += v;
        __syncthreads();
    }
    int run = part[t] - sum;   // exclusive prefix of this thread's chunk
    for (int i = 0; i < CH; ++i) {
        int idx = t * CH + i;
        if (idx < N) { offs[idx] = run; cursor[idx] = run; run += local[i]; }
    }
    if (t == 1023) offs[N] = part[1023];
}

// ---------------- bucket edges by dst ----------------
__global__ void scatter_k(const int* __restrict__ src, const int* __restrict__ dst,
                          const float* __restrict__ w, int* __restrict__ cursor,
                          int* __restrict__ srcs, float* __restrict__ wsort, int E) {
    int e = blockIdx.x * 256 + threadIdx.x;
    if (e < E) {
        int p = atomicAdd(&cursor[dst[e]], 1);
        srcs[p] = src[e];
        wsort[p] = w[e];
    }
}

// ---------------- fp32 GEMM: C[M,256] = A[M,256] @ B[256,256] ----------------
#define BM 64
#define BN 64
#define BK 16
__global__ __launch_bounds__(256) void gemm_k(const float* __restrict__ A,
                                              const float* __restrict__ B,
                                              float* __restrict__ C, int M) {
    __shared__ float As[BK][BM];
    __shared__ float Bs[BK][BN];
    int tid = threadIdx.x;
    int bm = blockIdx.x * BM;
    int bn = blockIdx.y * BN;
    int tx = tid & 15, ty = tid >> 4;
    float acc[4][4] = {};
    for (int k0 = 0; k0 < D; k0 += BK) {
        {   // A tile: rows bm..bm+63, cols k0..k0+15 -> As[k][m] (transposed)
            int r  = tid >> 2;
            int c4 = (tid & 3) * 4;
            float4 v = *(const float4*)&A[(size_t)(bm + r) * D + k0 + c4];
            As[c4 + 0][r] = v.x; As[c4 + 1][r] = v.y;
            As[c4 + 2][r] = v.z; As[c4 + 3][r] = v.w;
        }
        {   // B tile: rows k0..k0+15, cols bn..bn+63
            int r  = tid >> 4;
            int c4 = (tid & 15) * 4;
            *(float4*)&Bs[r][c4] = *(const float4*)&B[(size_t)(k0 + r) * D + bn + c4];
        }
        __syncthreads();
#pragma unroll
        for (int k = 0; k < BK; ++k) {
            float a[4], b[4];
#pragma unroll
            for (int i = 0; i < 4; ++i) a[i] = As[k][ty * 4 + i];
#pragma unroll
            for (int j = 0; j < 4; ++j) b[j] = Bs[k][tx * 4 + j];
#pragma unroll
            for (int i = 0; i < 4; ++i)
#pragma unroll
                for (int j = 0; j < 4; ++j) acc[i][j] = fmaf(a[i], b[j], acc[i][j]);
        }
        __syncthreads();
    }
#pragma unroll
    for (int i = 0; i < 4; ++i) {
        float4 v = make_float4(acc[i][0], acc[i][1], acc[i][2], acc[i][3]);
        *(float4*)&C[(size_t)(bm + ty * 4 + i) * D + bn + tx * 4] = v;
    }
}

// ---------------- SpMM (CSR by dst) + bias + ReLU ----------------
__global__ __launch_bounds__(256) void spmm_k(const float* __restrict__ h,
                                              const int* __restrict__ srcs,
                                              const float* __restrict__ wv,
                                              const int* __restrict__ offs,
                                              const float* __restrict__ bias,
                                              float* __restrict__ out) {
    int node = blockIdx.x;
    int t = threadIdx.x;           // feature index 0..255
    int beg = offs[node], end = offs[node + 1];
    __shared__ int   s_src[256];
    __shared__ float s_w[256];
    float acc = 0.f;
    for (int base = beg; base < end; base += 256) {
        int n = min(256, end - base);
        if (t < n) { s_src[t] = srcs[base + t]; s_w[t] = wv[base + t]; }
        __syncthreads();
        int i = 0;
        for (; i + 4 <= n; i += 4) {
            float a0 = h[(size_t)s_src[i]     * D + t];
            float a1 = h[(size_t)s_src[i + 1] * D + t];
            float a2 = h[(size_t)s_src[i + 2] * D + t];
            float a3 = h[(size_t)s_src[i + 3] * D + t];
            acc = fmaf(s_w[i],     a0, acc);
            acc = fmaf(s_w[i + 1], a1, acc);
            acc = fmaf(s_w[i + 2], a2, acc);
            acc = fmaf(s_w[i + 3], a3, acc);
        }
        for (; i < n; ++i) acc = fmaf(s_w[i], h[(size_t)s_src[i] * D + t], acc);
        __syncthreads();
    }
    out[(size_t)node * D + t] = fmaxf(acc + bias[t], 0.f);
}

// ---------------- cluster MLP + softmax (1 wave per node) ----------------
__global__ __launch_bounds__(64) void cluster_k(const float* __restrict__ h,
                                                const float* __restrict__ Wm,
                                                const float* __restrict__ bm,
                                                float* __restrict__ s_out) {
    int node = blockIdx.x;
    int lane = threadIdx.x;   // 0..63
    float4 hv = *(const float4*)&h[(size_t)node * D + lane * 4];
    float p[KCL];
#pragma unroll
    for (int j = 0; j < KCL; ++j) p[j] = 0.f;
    const float* hp = (const float*)&hv;
#pragma unroll
    for (int u = 0; u < 4; ++u) {
        float hval = hp[u];
        const float4* wrow = (const float4*)&Wm[(size_t)(lane * 4 + u) * KCL];
#pragma unroll
        for (int q = 0; q < 4; ++q) {
            float4 wv = wrow[q];
            p[q * 4 + 0] = fmaf(hval, wv.x, p[q * 4 + 0]);
            p[q * 4 + 1] = fmaf(hval, wv.y, p[q * 4 + 1]);
            p[q * 4 + 2] = fmaf(hval, wv.z, p[q * 4 + 2]);
            p[q * 4 + 3] = fmaf(hval, wv.w, p[q * 4 + 3]);
        }
    }
#pragma unroll
    for (int off = 32; off; off >>= 1)
#pragma unroll
        for (int j = 0; j < KCL; ++j) p[j] += __shfl_xor(p[j], off, 64);
    if (lane == 0) {
        float mx = -1e30f;
#pragma unroll
        for (int j = 0; j < KCL; ++j) { p[j] += bm[j]; mx = fmaxf(mx, p[j]); }
        float sum = 0.f;
#pragma unroll
        for (int j = 0; j < KCL; ++j) { p[j] = __expf(p[j] - mx); sum += p[j]; }
        float inv = 1.f / sum;
#pragma unroll
        for (int j = 0; j < KCL; ++j) s_out[(size_t)node * KCL + j] = p[j] * inv;
    }
}

// ---------------- diag(s^T s) partial reduce ----------------
__global__ __launch_bounds__(256) void sqred_k(const float* __restrict__ s,
                                               float* __restrict__ diag, int N) {
    int t = threadIdx.x;
    int j = t & 15;       // cluster
    int g = t >> 4;       // group 0..15
    float acc = 0.f;
    for (int i = blockIdx.x * 16 + g; i < N; i += gridDim.x * 16) {
        float v = s[(size_t)i * KCL + j];
        acc = fmaf(v, v, acc);
    }
    __shared__ float red[16][17];
    red[g][j] = acc;
    __syncthreads();
    if (g == 0) {
        float a = red[0][j];
#pragma unroll
        for (int gg = 1; gg < 16; ++gg) a += red[gg][j];
        atomicAdd(&diag[j], a);
    }
}

// ---------------- final loss ----------------
__global__ void loss_k(const float* __restrict__ diag, float* __restrict__ out, int N) {
    if (threadIdx.x == 0 && blockIdx.x == 0) {
        float s = 0.f;
#pragma unroll
        for (int j = 0; j < KCL; ++j) s += sqrtf(diag[j] + EPS);
        out[0] = -s / sqrtf((float)N * (float)KCL);
    }
}

extern "C" void kernel_launch(void* const* d_in, const int* in_sizes, int n_in,
                              void* d_out, int out_size, void* d_ws, size_t ws_size,
                              hipStream_t stream) {
    const float* x  = (const float*)d_in[0];
    const float* ew = (const float*)d_in[1];
    const float* W1 = (const float*)d_in[2];
    const float* b1 = (const float*)d_in[3];
    const float* W2 = (const float*)d_in[4];
    const float* b2 = (const float*)d_in[5];
    const float* Wm = (const float*)d_in[6];
    const float* bm = (const float*)d_in[7];
    const int*   ei = (const int*)d_in[8];

    const int N = in_sizes[0] / D;       // 12288
    const int E = in_sizes[1];           // 393216
    const int* src = ei;
    const int* dst = ei + E;

    float* out = (float*)d_out;

    // ws layout
    char* ws = (char*)d_ws;
    float* G      = (float*)ws;                     ws += (size_t)N * D * 4;   // gemm out
    float* H      = (float*)ws;                     ws += (size_t)N * D * 4;   // conv out
    int*   counts = (int*)ws;                       ws += (size_t)N * 4;
    int*   offs   = (int*)ws;                       ws += (size_t)(N + 1) * 4;
    int*   cursor = (int*)ws;                       ws += (size_t)N * 4;
    int*   srcs   = (int*)ws;                       ws += (size_t)E * 4;
    float* wsort  = (float*)ws;                     ws += (size_t)E * 4;
    float* diag   = (float*)ws;                     ws += 64;

    int gE = (E + 255) / 256;
    int gN = (N + 255) / 256;

    // CSR build
    zero_k<<<gN, 256, 0, stream>>>(counts, diag, N);
    hist_k<<<gE, 256, 0, stream>>>(dst, counts, E);
    scan_k<<<1, 1024, 0, stream>>>(counts, offs, cursor, N);
    scatter_k<<<gE, 256, 0, stream>>>(src, dst, ew, cursor, srcs, wsort, E);

    dim3 ggrid(N / BM, D / BN);
    // conv1: G = x @ W1 ; H = relu(scatter(G) + b1)
    gemm_k<<<ggrid, 256, 0, stream>>>(x, W1, G, N);
    spmm_k<<<N, 256, 0, stream>>>(G, srcs, wsort, offs, b1, H);
    // conv2
    gemm_k<<<ggrid, 256, 0, stream>>>(H, W2, G, N);
    spmm_k<<<N, 256, 0, stream>>>(G, srcs, wsort, offs, b2, H);
    // cluster assignment -> s (d_out), then loss
    cluster_k<<<N, 64, 0, stream>>>(H, Wm, bm, out);
    sqred_k<<<64, 256, 0, stream>>>(out, diag, N);
    loss_k<<<1, 64, 0, stream>>>(diag, out + (size_t)N * KCL, N);
}

// Round 2
// 285.851 us; speedup vs baseline: 1.0982x; 1.0982x over previous
//
#include <hip/hip_runtime.h>
#include <hip/hip_bf16.h>
#include <hip/hip_fp16.h>

// Problem constants: N=12288, E=393216, D=256, K=16
#define D 256
#define KCL 16
#define EPS 1e-15f

typedef __attribute__((ext_vector_type(8))) short short8;
typedef __attribute__((ext_vector_type(4))) float f32x4;

__device__ inline short bfhi(float v) {
    __hip_bfloat16 b = __float2bfloat16(v);
    return __builtin_bit_cast(short, b);
}
__device__ inline float bf2f(short s) {
    __hip_bfloat16 b = __builtin_bit_cast(__hip_bfloat16, s);
    return __bfloat162float(b);
}

// ---------------- zero counts + diag ----------------
__global__ void zero_k(int* __restrict__ counts, float* __restrict__ diag, int N) {
    int i = blockIdx.x * 256 + threadIdx.x;
    if (i < N) counts[i] = 0;
    if (i < KCL) diag[i] = 0.f;
}

// ---------------- degree histogram ----------------
__global__ void hist_k(const int* __restrict__ dst, int* __restrict__ counts, int E) {
    int e = blockIdx.x * 256 + threadIdx.x;
    if (e < E) atomicAdd(&counts[dst[e]], 1);
}

// ---------------- exclusive scan (single block, 1024 threads) ----------------
__global__ __launch_bounds__(1024) void scan_k(const int* __restrict__ counts,
                                               int* __restrict__ offs,
                                               int* __restrict__ cursor, int N) {
    __shared__ int part[1024];
    int t = threadIdx.x;
    const int CH = (N + 1023) >> 10;
    int local[16];
    int sum = 0;
    for (int i = 0; i < CH; ++i) {
        int idx = t * CH + i;
        int c = (idx < N) ? counts[idx] : 0;
        local[i] = c; sum += c;
    }
    part[t] = sum;
    __syncthreads();
    for (int off = 1; off < 1024; off <<= 1) {
        int v = (t >= off) ? part[t - off] : 0;
        __syncthreads();
        part[t] += v;
        __syncthreads();
    }
    int run = part[t] - sum;
    for (int i = 0; i < CH; ++i) {
        int idx = t * CH + i;
        if (idx < N) { offs[idx] = run; cursor[idx] = run; run += local[i]; }
    }
    if (t == 1023) offs[N] = part[1023];
}

// ---------------- bucket edges by dst ----------------
__global__ void scatter_k(const int* __restrict__ src, const int* __restrict__ dst,
                          const float* __restrict__ w, int* __restrict__ cursor,
                          int* __restrict__ srcs, float* __restrict__ wsort, int E) {
    int e = blockIdx.x * 256 + threadIdx.x;
    if (e < E) {
        int p = atomicAdd(&cursor[dst[e]], 1);
        srcs[p] = src[e];
        wsort[p] = w[e];
    }
}

// ---------------- split-bf16 MFMA GEMM: C[M,256] = A[M,256] @ B[256,256], fp16 out ----
#define GBM 64
#define GBN 64
#define GBK 32
#define APAD 40
__global__ __launch_bounds__(256) void gemm_k(const float* __restrict__ A,
                                              const float* __restrict__ B,
                                              __half* __restrict__ C, int M) {
    __shared__ short Ah[GBM][APAD];
    __shared__ short Al[GBM][APAD];
    __shared__ short Bh[GBN][APAD];   // stored transposed: [col][k]
    __shared__ short Bl[GBN][APAD];
    int tid = threadIdx.x;
    int lane = tid & 63, w = tid >> 6;
    int bm = blockIdx.x * GBM, bn = blockIdx.y * GBN;
    f32x4 acc[4];
#pragma unroll
    for (int i = 0; i < 4; ++i) acc[i] = (f32x4){0.f, 0.f, 0.f, 0.f};

    for (int kk = 0; kk < D; kk += GBK) {
        {   // stage A tile (64 rows x 32 k), split hi/lo
            int r = tid >> 2, c = (tid & 3) * 8;
            const float* ap = &A[(size_t)(bm + r) * D + kk + c];
            float4 v0 = *(const float4*)ap;
            float4 v1 = *(const float4*)(ap + 4);
            float vv[8] = {v0.x, v0.y, v0.z, v0.w, v1.x, v1.y, v1.z, v1.w};
#pragma unroll
            for (int j = 0; j < 8; ++j) {
                short h = bfhi(vv[j]);
                Ah[r][c + j] = h;
                Al[r][c + j] = bfhi(vv[j] - bf2f(h));
            }
        }
        {   // stage B tile (32 k x 64 cols) transposed to [col][k], split hi/lo
            int k = tid >> 3, c = (tid & 7) * 8;
            const float* bp = &B[(size_t)(kk + k) * D + bn + c];
            float4 v0 = *(const float4*)bp;
            float4 v1 = *(const float4*)(bp + 4);
            float vv[8] = {v0.x, v0.y, v0.z, v0.w, v1.x, v1.y, v1.z, v1.w};
#pragma unroll
            for (int j = 0; j < 8; ++j) {
                short h = bfhi(vv[j]);
                Bh[c + j][k] = h;
                Bl[c + j][k] = bfhi(vv[j] - bf2f(h));
            }
        }
        __syncthreads();
        int ar = w * 16 + (lane & 15);
        int kq = (lane >> 4) * 8;
        short8 a_h = *(const short8*)&Ah[ar][kq];
        short8 a_l = *(const short8*)&Al[ar][kq];
#pragma unroll
        for (int nf = 0; nf < 4; ++nf) {
            int bc = nf * 16 + (lane & 15);
            short8 b_h = *(const short8*)&Bh[bc][kq];
            short8 b_l = *(const short8*)&Bl[bc][kq];
            acc[nf] = __builtin_amdgcn_mfma_f32_16x16x32_bf16(a_h, b_h, acc[nf], 0, 0, 0);
            acc[nf] = __builtin_amdgcn_mfma_f32_16x16x32_bf16(a_h, b_l, acc[nf], 0, 0, 0);
            acc[nf] = __builtin_amdgcn_mfma_f32_16x16x32_bf16(a_l, b_h, acc[nf], 0, 0, 0);
        }
        __syncthreads();
    }
    // epilogue: C/D layout col=lane&15, row=(lane>>4)*4+r  [m89-verified]
    int rbase = bm + w * 16 + (lane >> 4) * 4;
    int cb = bn + (lane & 15);
#pragma unroll
    for (int nf = 0; nf < 4; ++nf)
#pragma unroll
        for (int r = 0; r < 4; ++r)
            C[(size_t)(rbase + r) * D + cb + nf * 16] = __float2half(acc[nf][r]);
}

// ---------------- SpMM (CSR by dst), fp16 gather + bias + ReLU ----------------
__global__ __launch_bounds__(256) void spmm_k(const __half* __restrict__ h,
                                              const int* __restrict__ srcs,
                                              const float* __restrict__ wv,
                                              const int* __restrict__ offs,
                                              const float* __restrict__ bias,
                                              float* __restrict__ out) {
    int node = blockIdx.x;
    int t = threadIdx.x;           // feature index 0..255
    int beg = offs[node], end = offs[node + 1];
    __shared__ int   s_src[256];
    __shared__ float s_w[256];
    float acc = 0.f;
    for (int base = beg; base < end; base += 256) {
        int n = min(256, end - base);
        if (t < n) { s_src[t] = srcs[base + t]; s_w[t] = wv[base + t]; }
        __syncthreads();
        int i = 0;
        for (; i + 4 <= n; i += 4) {
            float a0 = __half2float(h[(size_t)s_src[i]     * D + t]);
            float a1 = __half2float(h[(size_t)s_src[i + 1] * D + t]);
            float a2 = __half2float(h[(size_t)s_src[i + 2] * D + t]);
            float a3 = __half2float(h[(size_t)s_src[i + 3] * D + t]);
            acc = fmaf(s_w[i],     a0, acc);
            acc = fmaf(s_w[i + 1], a1, acc);
            acc = fmaf(s_w[i + 2], a2, acc);
            acc = fmaf(s_w[i + 3], a3, acc);
        }
        for (; i < n; ++i) acc = fmaf(s_w[i], __half2float(h[(size_t)s_src[i] * D + t]), acc);
        __syncthreads();
    }
    out[(size_t)node * D + t] = fmaxf(acc + bias[t], 0.f);
}

// ---------------- cluster MLP + softmax (1 wave per node) ----------------
__global__ __launch_bounds__(64) void cluster_k(const float* __restrict__ h,
                                                const float* __restrict__ Wm,
                                                const float* __restrict__ bm,
                                                float* __restrict__ s_out) {
    int node = blockIdx.x;
    int lane = threadIdx.x;
    float4 hv = *(const float4*)&h[(size_t)node * D + lane * 4];
    float p[KCL];
#pragma unroll
    for (int j = 0; j < KCL; ++j) p[j] = 0.f;
    const float* hp = (const float*)&hv;
#pragma unroll
    for (int u = 0; u < 4; ++u) {
        float hval = hp[u];
        const float4* wrow = (const float4*)&Wm[(size_t)(lane * 4 + u) * KCL];
#pragma unroll
        for (int q = 0; q < 4; ++q) {
            float4 wv = wrow[q];
            p[q * 4 + 0] = fmaf(hval, wv.x, p[q * 4 + 0]);
            p[q * 4 + 1] = fmaf(hval, wv.y, p[q * 4 + 1]);
            p[q * 4 + 2] = fmaf(hval, wv.z, p[q * 4 + 2]);
            p[q * 4 + 3] = fmaf(hval, wv.w, p[q * 4 + 3]);
        }
    }
#pragma unroll
    for (int off = 32; off; off >>= 1)
#pragma unroll
        for (int j = 0; j < KCL; ++j) p[j] += __shfl_xor(p[j], off, 64);
    if (lane == 0) {
        float mx = -1e30f;
#pragma unroll
        for (int j = 0; j < KCL; ++j) { p[j] += bm[j]; mx = fmaxf(mx, p[j]); }
        float sum = 0.f;
#pragma unroll
        for (int j = 0; j < KCL; ++j) { p[j] = __expf(p[j] - mx); sum += p[j]; }
        float inv = 1.f / sum;
#pragma unroll
        for (int j = 0; j < KCL; ++j) s_out[(size_t)node * KCL + j] = p[j] * inv;
    }
}

// ---------------- diag(s^T s) partial reduce ----------------
__global__ __launch_bounds__(256) void sqred_k(const float* __restrict__ s,
                                               float* __restrict__ diag, int N) {
    int t = threadIdx.x;
    int j = t & 15;
    int g = t >> 4;
    float acc = 0.f;
    for (int i = blockIdx.x * 16 + g; i < N; i += gridDim.x * 16) {
        float v = s[(size_t)i * KCL + j];
        acc = fmaf(v, v, acc);
    }
    __shared__ float red[16][17];
    red[g][j] = acc;
    __syncthreads();
    if (g == 0) {
        float a = red[0][j];
#pragma unroll
        for (int gg = 1; gg < 16; ++gg) a += red[gg][j];
        atomicAdd(&diag[j], a);
    }
}

// ---------------- final loss ----------------
__global__ void loss_k(const float* __restrict__ diag, float* __restrict__ out, int N) {
    if (threadIdx.x == 0 && blockIdx.x == 0) {
        float s = 0.f;
#pragma unroll
        for (int j = 0; j < KCL; ++j) s += sqrtf(diag[j] + EPS);
        out[0] = -s / sqrtf((float)N * (float)KCL);
    }
}

extern "C" void kernel_launch(void* const* d_in, const int* in_sizes, int n_in,
                              void* d_out, int out_size, void* d_ws, size_t ws_size,
                              hipStream_t stream) {
    const float* x  = (const float*)d_in[0];
    const float* ew = (const float*)d_in[1];
    const float* W1 = (const float*)d_in[2];
    const float* b1 = (const float*)d_in[3];
    const float* W2 = (const float*)d_in[4];
    const float* b2 = (const float*)d_in[5];
    const float* Wm = (const float*)d_in[6];
    const float* bm = (const float*)d_in[7];
    const int*   ei = (const int*)d_in[8];

    const int N = in_sizes[0] / D;       // 12288
    const int E = in_sizes[1];           // 393216
    const int* src = ei;
    const int* dst = ei + E;

    float* out = (float*)d_out;

    // ws layout
    char* ws = (char*)d_ws;
    __half* G   = (__half*)ws;                      ws += (size_t)N * D * 2;   // gemm out (fp16)
    float* H      = (float*)ws;                     ws += (size_t)N * D * 4;   // conv out
    int*   counts = (int*)ws;                       ws += (size_t)N * 4;
    int*   offs   = (int*)ws;                       ws += (size_t)(N + 1) * 4;
    int*   cursor = (int*)ws;                       ws += (size_t)N * 4;
    int*   srcs   = (int*)ws;                       ws += (size_t)E * 4;
    float* wsort  = (float*)ws;                     ws += (size_t)E * 4;
    float* diag   = (float*)ws;                     ws += 64;

    int gE = (E + 255) / 256;
    int gN = (N + 255) / 256;

    // CSR build
    zero_k<<<gN, 256, 0, stream>>>(counts, diag, N);
    hist_k<<<gE, 256, 0, stream>>>(dst, counts, E);
    scan_k<<<1, 1024, 0, stream>>>(counts, offs, cursor, N);
    scatter_k<<<gE, 256, 0, stream>>>(src, dst, ew, cursor, srcs, wsort, E);

    dim3 ggrid(N / GBM, D / GBN);
    // conv1: G = fp16(x @ W1) ; H = relu(scatter(G) + b1)
    gemm_k<<<ggrid, 256, 0, stream>>>(x, W1, G, N);
    spmm_k<<<N, 256, 0, stream>>>(G, srcs, wsort, offs, b1, H);
    // conv2
    gemm_k<<<ggrid, 256, 0, stream>>>(H, W2, G, N);
    spmm_k<<<N, 256, 0, stream>>>(G, srcs, wsort, offs, b2, H);
    // cluster assignment -> s (d_out), then loss
    cluster_k<<<N, 64, 0, stream>>>(H, Wm, bm, out);
    sqred_k<<<64, 256, 0, stream>>>(out, diag, N);
    loss_k<<<1, 64, 0, stream>>>(diag, out + (size_t)N * KCL, N);
}